// Round 8
// baseline (665.553 us; speedup 1.0000x reference)
//
#include <hip/hip_runtime.h>

// Boosted neural LDPC min-sum decoder, MI355X — single persistent cooperative
// kernel with hand-rolled grid barrier; int8-message state; z-fastest layout.
// Sizes fixed by setup_inputs(): B=32, Z=384, N=68, M=46, dc=7, E=322, iters=8.
#define B_   32
#define Z_   384
#define N_   68
#define M_   46
#define DC_  7
#define E_   (M_ * DC_)      // 322
#define ZN   (Z_ * N_)       // 26112
#define ZM   (Z_ * M_)       // 17664
#define GB_  256             // persistent grid blocks (cooperative, 1/CU)
#define ZN_S (ZN / 8)        // 3264  per-slice items, pass A
#define ZM_S (ZM / 8)        // 2208  per-slice items, pass B

// ---- workspace layout (int32 offsets), all big arrays z-fastest ----
#define XAT_OFF   0                          // float xat[B*ZN]
#define LT_OFF    (B_ * ZN)                  // float lt[B*ZN]
#define MSG_OFF   (2 * B_ * ZN)              // int2  msg[B*ZM]  (7 sbyte messages/check)
#define EVS_OFF   (MSG_OFF + 2 * B_ * ZM)    // int   evs[E]     vn | s<<7   (check-major)
#define OFFS_OFF  (EVS_OFF + E_)             // int   offs[N+1]  CSR per variable
#define LST_OFF   (OFFS_OFF + N_ + 1)        // int   lists[E]   s | m<<9 | j<<15
#define BAR_OFF   (LST_OFF + E_)             // unsigned cnt, gen
#define WS_INTS   (BAR_OFF + 2)              // ~2.80M ints ≈ 11.2 MB

// msg[m][z] = 8 bytes, byte j = c2v message on edge j in half-steps, sign applied,
// range [-15,15]. Exact integers -> all fp arithmetic orders identical to JAX ref.

// ==================== merged pre-transpose + table build ====================
// Blocks 0..191: xat[b][n][z] = xa[b][z][n] (XCD-swizzled). Block 192: tables
// + barrier-word init.
__global__ __launch_bounds__(384)
void k_pre_tables(const float* __restrict__ xa,
                  const int* __restrict__ vn_idx, const int* __restrict__ shifts,
                  int* __restrict__ ws, float* __restrict__ xat_dst)
{
    const int tid = threadIdx.x;
    if (blockIdx.x == B_ * 6) {
        // ---- table build (1 block) ----
        __shared__ int evs[E_];
        __shared__ int offs[N_ + 1];
        __shared__ int lists[E_];
        if (tid < E_) evs[tid] = vn_idx[tid] | (shifts[tid] << 7);
        if (tid == 0) { ws[BAR_OFF] = 0; ws[BAR_OFF + 1] = 0; }  // barrier init
        __syncthreads();
        if (tid < N_) {
            int c = 0;
            for (int e = 0; e < E_; ++e) c += ((evs[e] & 127) == tid);
            offs[tid + 1] = c;
        }
        if (tid == 0) offs[0] = 0;
        __syncthreads();
        if (tid == 0) { for (int n = 0; n < N_; ++n) offs[n + 1] += offs[n]; }
        __syncthreads();
        if (tid < N_) {
            int p = offs[tid];
            for (int e = 0; e < E_; ++e) {
                int rec = evs[e];
                if ((rec & 127) == tid) {
                    int s = rec >> 7;
                    lists[p++] = s | ((e / DC_) << 9) | ((e % DC_) << 15);
                }
            }
        }
        __syncthreads();
        if (tid < E_) { ws[EVS_OFF + tid] = evs[tid]; ws[LST_OFF + tid] = lists[tid]; }
        if (tid < N_ + 1) ws[OFFS_OFF + tid] = offs[tid];
        return;
    }
    // ---- pre-transpose: block = swizzled (b, 64-z tile) ----
    __shared__ float tile[N_ * 65];           // [n][zl], pad 65 to break conflicts
    const int x = blockIdx.x & 7;
    const int k = blockIdx.x >> 3;            // 0..23
    const int b = x + 8 * (k & 3);            // b % 8 == x  -> XCD locality
    const int t = k >> 2;                     // 0..5
    const int z0 = t * 64;
    const float* src = xa + (size_t)b * ZN + (size_t)z0 * N_;
    for (int i = tid; i < 64 * N_; i += 384) {  // contiguous 17 KB read
        int r = i / N_, n = i - r * N_;
        tile[n * 65 + r] = src[i];
    }
    __syncthreads();
    float* dst = xat_dst + (size_t)b * ZN + z0;
    for (int i = tid; i < 64 * N_; i += 384) {
        int n = i >> 6, zl = i & 63;
        dst[n * Z_ + zl] = tile[n * 65 + zl];
    }
}

// ==================== hand-rolled grid barrier (sense = monotonic phase) ====
__device__ __forceinline__ void gbar(unsigned* cnt, unsigned* gen, unsigned phase)
{
    __syncthreads();                          // block's stores issued (vmcnt drained)
    if (threadIdx.x == 0) {
        __threadfence();                      // agent release: XCD L2 writeback
        unsigned old = __hip_atomic_fetch_add(cnt, 1u, __ATOMIC_ACQ_REL,
                                              __HIP_MEMORY_SCOPE_AGENT);
        if (old == (unsigned)gridDim.x - 1u) {
            __hip_atomic_store(cnt, 0u, __ATOMIC_RELAXED, __HIP_MEMORY_SCOPE_AGENT);
            __hip_atomic_store(gen, phase, __ATOMIC_RELEASE, __HIP_MEMORY_SCOPE_AGENT);
        } else {
            while (__hip_atomic_load(gen, __ATOMIC_ACQUIRE,
                                     __HIP_MEMORY_SCOPE_AGENT) < phase) {
                __builtin_amdgcn_s_sleep(2);  // ~128 cycles backoff
            }
        }
        __threadfence();                      // agent acquire: invalidate stale
    }
    __syncthreads();
}

// ==================== pass bodies (R7 logic, slice-local) ====================
// pass B: check-node update for batch b, slice sl of [0, ZM).
__device__ __forceinline__ void passB_slice(int b, int sl,
                                            const float* __restrict__ src_g,
                                            int2* __restrict__ msg, float w,
                                            const int* __restrict__ evs,
                                            int use_init, int tid)
{
    const float* src = src_g + (size_t)b * ZN;
    int2* mpb = msg + (size_t)b * ZM;
    const int lo = sl * ZM_S, hi = lo + ZM_S;
    for (int l = lo + tid; l < hi; l += 1024) {
        const int m = l / Z_;
        const int z = l - m * Z_;
        const int2 old = use_init ? make_int2(0, 0) : mpb[l];

        float m1 = 1e30f, m2 = 1e30f;
        int f = 0, negb = 0;
        #pragma unroll
        for (int j = 0; j < DC_; ++j) {
            int rec = evs[m * DC_ + j];
            int vn = rec & 127;
            int s  = rec >> 7;
            int zr = z + s; if (zr >= Z_) zr -= Z_;
            int w32 = (j < 4) ? old.x : old.y;
            int c2 = (w32 << (24 - 8 * (j & 3))) >> 24;   // sign-extended byte j
            // identical operand order to JAX: fl(fl(llr + tot) - c2v), then clip
            float v = src[vn * Z_ + zr] - 0.5f * (float)c2;
            v = fminf(fmaxf(v, -20.0f), 20.0f);
            negb |= (v < 0.0f) << j;
            float a = fabsf(v);
            if (a < m1) { m2 = m1; m1 = a; f = j; }
            else if (a < m2) { m2 = a; }
        }
        // quantize-STE forward: clip(rint(2*w*min)/2, +-7.5), kept as int half-steps
        float r1 = fminf(fmaxf(rintf(w * m1 * 2.0f), -15.0f), 15.0f);
        float r2 = fminf(fmaxf(rintf(w * m2 * 2.0f), -15.0f), 15.0f);
        const int q1 = (int)r1, q2 = (int)r2;
        const int par = __popc(negb);
        int plo = 0, phi = 0;
        #pragma unroll
        for (int j = 0; j < DC_; ++j) {
            int q  = (j == f) ? q2 : q1;
            int sj = (par - ((negb >> j) & 1)) & 1;   // parity of other edges' signs
            int mj = sj ? -q : q;
            if (j < 4) plo |= (mj & 255) << (8 * j);
            else       phi |= (mj & 255) << (8 * (j - 4));
        }
        mpb[l] = make_int2(plo, phi);
    }
}

// pass A: variable totals for batch b, slice sl of [0, ZN); dst layout == out.
__device__ __forceinline__ void passA_slice(int b, int sl,
                                            const float* __restrict__ xat,
                                            const int2* __restrict__ msg,
                                            float* __restrict__ dst,
                                            const int* __restrict__ offs,
                                            const int* __restrict__ lists, int tid)
{
    const signed char* mb = (const signed char*)(msg + (size_t)b * ZM);
    const float* xb = xat + (size_t)b * ZN;
    float* db = dst + (size_t)b * ZN;
    const int lo = sl * ZN_S, hi = lo + ZN_S;
    for (int l = lo + tid; l < hi; l += 1024) {
        const int n = l / Z_;
        const int z = l - n * Z_;
        const int o = offs[n], e = offs[n + 1];   // wave-uniform (rows 64-aligned)
        int t2 = 0;
        for (int k = o; k < e; ++k) {
            int rec = lists[k];
            int s = rec & 511;
            int m = (rec >> 9) & 63;
            int j = (rec >> 15) & 7;
            int zs = z - s; if (zs < 0) zs += Z_;
            t2 += (int)mb[((m * Z_ + zs) << 3) + j];  // exact int half-steps
        }
        db[l] = xb[l] + 0.5f * (float)t2;             // fl(llr + tot)
    }
}

// ==================== persistent cooperative kernel ====================
// block g: batch b = (g&7) + 8*((g>>3)&3)  (b%8 == g%8 -> XCD locality),
// slice sl = g>>5 covering 1/8 of the batch's items.
__global__ __launch_bounds__(1024)
void k_persist(const float* __restrict__ xat, const float* __restrict__ cw,
               int* __restrict__ ws, int2* __restrict__ msg,
               float* __restrict__ lt, float* __restrict__ out, int iters)
{
    __shared__ int evs[E_];
    __shared__ int lists[E_];
    __shared__ int offs[N_ + 1];
    __shared__ float wlds[8];
    const int tid = threadIdx.x;
    if (tid < E_) { evs[tid] = ws[EVS_OFF + tid]; lists[tid] = ws[LST_OFF + tid]; }
    if (tid < N_ + 1) offs[tid] = ws[OFFS_OFF + tid];
    if (tid < 8 && tid < iters) wlds[tid] = cw[tid];
    __syncthreads();

    const int x  = blockIdx.x & 7;
    const int kk = blockIdx.x >> 3;
    const int b  = x + 8 * (kk & 3);
    const int sl = kk >> 2;                    // 0..7
    unsigned* cnt = (unsigned*)(ws + BAR_OFF);
    unsigned* gen = (unsigned*)(ws + BAR_OFF + 1);
    unsigned phase = 0;

    // it = 0: lt_old == xat, all old c2v == 0
    passB_slice(b, sl, xat, msg, wlds[0], evs, 1, tid);
    for (int it = 1; it < iters; ++it) {
        gbar(cnt, gen, ++phase);
        passA_slice(b, sl, xat, msg, lt, offs, lists, tid);
        gbar(cnt, gen, ++phase);
        passB_slice(b, sl, lt, msg, wlds[it], evs, 0, tid);
    }
    gbar(cnt, gen, ++phase);
    passA_slice(b, sl, xat, msg, out, offs, lists, tid);  // out layout == lt layout
}

// ==================== fallback: single-block-per-batch kernel (small ws) ====================
#define INIT_STATE ((16u << 10) | (16u << 15))
__device__ __forceinline__ int decode2(unsigned st, int j) {
    int neg   = (st >> j) & 1;
    int q1    = (int)((st >> 10) & 31) - 16;
    int q2    = (int)((st >> 15) & 31) - 16;
    int first = (int)((st >> 7) & 7);
    int q     = (j == first) ? q2 : q1;
    int par   = (__popc(st & 127u) - neg) & 1;
    return par ? -q : q;
}

__global__ __launch_bounds__(1024)
void ldpc_decode_kernel(const float* __restrict__ xa,
                        const float* __restrict__ cw,
                        const int*   __restrict__ vn_idx,
                        const int*   __restrict__ shifts,
                        float* out, int iters)
{
    __shared__ short tot[ZN];
    __shared__ int   evs[E_];
    __shared__ int   offs[N_ + 1];
    __shared__ int   lists[E_];
    __shared__ float wlds[8];

    const int tid = threadIdx.x;
    const int b   = blockIdx.x;
    const float* xab = xa + (size_t)b * ZN;
    float* outb = out + (size_t)b * ZN;
    int* stateg = (int*)outb;

    if (tid < E_) evs[tid] = vn_idx[tid] | (shifts[tid] << 7);
    if (tid < iters && tid < 8) wlds[tid] = cw[tid];
    __syncthreads();
    if (tid < N_) {
        int c = 0;
        for (int e = 0; e < E_; ++e) c += ((evs[e] & 127) == tid);
        offs[tid + 1] = c;
    }
    if (tid == 0) offs[0] = 0;
    __syncthreads();
    if (tid == 0) { for (int n = 0; n < N_; ++n) offs[n + 1] += offs[n]; }
    __syncthreads();
    if (tid < N_) {
        int p = offs[tid];
        for (int e = 0; e < E_; ++e) {
            int rec = evs[e];
            if ((rec & 127) == tid) {
                int s = rec >> 7;
                lists[p++] = s | ((e / DC_) << 9) | ((e % DC_) << 15);
            }
        }
    }
    __syncthreads();

    for (int i = tid; i < ZM; i += 1024) stateg[i] = (int)INIT_STATE;
    __syncthreads();

    for (int it = 0; it < iters; ++it) {
        for (int i = tid; i < ZN; i += 1024) {
            int z = i / N_, n = i - z * N_, t2 = 0;
            int kend = offs[n + 1];
            for (int k = offs[n]; k < kend; ++k) {
                int rec = lists[k];
                int s = rec & 511, m = (rec >> 9) & 63, j = rec >> 15;
                int zs = z - s; if (zs < 0) zs += Z_;
                t2 += decode2((unsigned)stateg[zs * M_ + m], j);
            }
            tot[i] = (short)t2;
        }
        __syncthreads();
        const float w = wlds[it];
        for (int i = tid; i < ZM; i += 1024) {
            int z = i / M_, m = i - z * M_;
            unsigned st = (unsigned)stateg[i];
            float m1 = 1e30f, m2 = 1e30f;
            int f = 0, negb = 0;
            #pragma unroll
            for (int j = 0; j < DC_; ++j) {
                int rec = evs[m * DC_ + j];
                int vn = rec & 127, s = rec >> 7;
                int zr = z + s; if (zr >= Z_) zr -= Z_;
                int c2 = decode2(st, j);
                int idx = zr * N_ + vn;
                float v = (xab[idx] + 0.5f * (float)tot[idx]) - 0.5f * (float)c2;
                v = fminf(fmaxf(v, -20.0f), 20.0f);
                negb |= (v < 0.0f) << j;
                float a = fabsf(v);
                if (a < m1) { m2 = m1; m1 = a; f = j; }
                else if (a < m2) { m2 = a; }
            }
            float r1 = fminf(fmaxf(rintf(w * m1 * 2.0f), -15.0f), 15.0f);
            float r2 = fminf(fmaxf(rintf(w * m2 * 2.0f), -15.0f), 15.0f);
            stateg[i] = (int)(unsigned)(negb | (f << 7) | (((int)r1 + 16) << 10) | (((int)r2 + 16) << 15));
        }
        __syncthreads();
    }

    for (int i = tid; i < ZN; i += 1024) {
        int z = i / N_, n = i - z * N_, t2 = 0;
        int kend = offs[n + 1];
        for (int k = offs[n]; k < kend; ++k) {
            int rec = lists[k];
            int s = rec & 511, m = (rec >> 9) & 63, j = rec >> 15;
            int zs = z - s; if (zs < 0) zs += Z_;
            t2 += decode2((unsigned)stateg[zs * M_ + m], j);
        }
        tot[i] = (short)t2;
    }
    __syncthreads();
    for (int i = tid; i < ZN; i += 1024) {
        int n = i / Z_, z = i - n * Z_;
        outb[i] = xab[z * N_ + n] + 0.5f * (float)tot[z * N_ + n];
    }
}

extern "C" void kernel_launch(void* const* d_in, const int* in_sizes, int n_in,
                              void* d_out, int out_size, void* d_ws, size_t ws_size,
                              hipStream_t stream) {
    const float* xa = (const float*)d_in[0];
    const float* cw = (const float*)d_in[1];
    const int* vn   = (const int*)d_in[2];
    // d_in[3] = cn_idx: repeat(arange(M), dc) by construction — implicit.
    const int* sh   = (const int*)d_in[4];
    int iters = in_sizes[1];
    float* outp = (float*)d_out;

    if (ws_size >= (size_t)WS_INTS * sizeof(int)) {
        int*   ws  = (int*)d_ws;
        float* xat = (float*)d_ws + XAT_OFF;
        float* lt  = (float*)d_ws + LT_OFF;
        int2*  msg = (int2*)(ws + MSG_OFF);

        if (iters == 0) {   // out = transpose(xa); tables block is harmless
            hipLaunchKernelGGL(k_pre_tables, dim3(B_ * 6 + 1), dim3(384), 0, stream,
                               xa, vn, sh, ws, outp);
            return;
        }
        hipLaunchKernelGGL(k_pre_tables, dim3(B_ * 6 + 1), dim3(384), 0, stream,
                           xa, vn, sh, ws, xat);
        void* args[] = { (void*)&xat, (void*)&cw, (void*)&ws, (void*)&msg,
                         (void*)&lt, (void*)&outp, (void*)&iters };
        hipLaunchCooperativeKernel((const void*)k_persist, dim3(GB_), dim3(1024),
                                   args, 0, stream);
    } else {
        hipLaunchKernelGGL(ldpc_decode_kernel, dim3(B_), dim3(1024), 0, stream,
                           xa, cw, vn, sh, outp, iters);
    }
}

// Round 9
// 201.513 us; speedup vs baseline: 3.3028x; 3.3028x over previous
//
#include <hip/hip_runtime.h>

// Boosted neural LDPC min-sum decoder, MI355X — stream-ordered per-pass kernels
// (R7 skeleton), PLANE-MAJOR int8 messages, folded-offset tables, XCD swizzle.
// Sizes fixed by setup_inputs(): B=32, Z=384, N=68, M=46, dc=7, E=322, iters=8.
#define B_   32
#define Z_   384
#define N_   68
#define M_   46
#define DC_  7
#define E_   (M_ * DC_)      // 322
#define ZN   (Z_ * N_)       // 26112
#define ZM   (Z_ * M_)       // 17664
#define MSB  (DC_ * ZM)      // 123648 bytes of messages per batch (7 planes)

// ---- workspace layout (int32 offsets), all big arrays z-fastest ----
#define XAT_OFF   0                          // float xat[B*ZN]
#define LT_OFF    (B_ * ZN)                  // float lt[B*ZN]
#define MSG_OFF   (2 * B_ * ZN)              // sbyte msg[B][7][ZM]  (plane-major)
#define MSG_INTS  ((B_ * MSB + 3) / 4)
#define EVS_OFF   (MSG_OFF + MSG_INTS)       // int evs[E]    (vn*Z)<<9 | s   (check-major)
#define OFFS_OFF  (EVS_OFF + E_)             // int offs[N+1] CSR per variable
#define LST_OFF   (OFFS_OFF + N_ + 1)        // int lists[E]  (j*ZM+m*Z)<<9 | s
#define WS_INTS   (LST_OFF + E_)             // ~2.66M ints ≈ 10.6 MB

// msg[b][j][m*Z+z] = c2v message on edge j of check (m,z), sign applied, in
// half-steps, range [-15,15]. Exact ints -> fp arithmetic identical to JAX ref.

// ==================== merged pre-transpose + table build ====================
// Blocks 0..191: xat[b][n][z] = xa[b][z][n] (XCD-swizzled). Block 192: tables.
__global__ __launch_bounds__(384)
void k_pre_tables(const float* __restrict__ xa,
                  const int* __restrict__ vn_idx, const int* __restrict__ shifts,
                  int* __restrict__ ws, float* __restrict__ xat_dst)
{
    const int tid = threadIdx.x;
    if (blockIdx.x == B_ * 6) {
        // ---- table build (1 block) ----
        __shared__ int vnl[E_];
        __shared__ int shl[E_];
        __shared__ int offs[N_ + 1];
        if (tid < E_) { vnl[tid] = vn_idx[tid]; shl[tid] = shifts[tid]; }
        __syncthreads();
        if (tid < N_) {
            int c = 0;
            for (int e = 0; e < E_; ++e) c += (vnl[e] == tid);
            offs[tid + 1] = c;
        }
        if (tid == 0) offs[0] = 0;
        __syncthreads();
        if (tid == 0) { for (int n = 0; n < N_; ++n) offs[n + 1] += offs[n]; }
        __syncthreads();
        if (tid < E_) {
            // pass-B record: lt-offset folded -> (vn*Z)<<9 | s
            ws[EVS_OFF + tid] = (vnl[tid] * Z_ << 9) | shl[tid];
        }
        if (tid < N_ + 1) ws[OFFS_OFF + tid] = offs[tid];
        if (tid < N_) {
            int p = offs[tid];
            for (int e = 0; e < E_; ++e) {
                if (vnl[e] == tid) {
                    int m = e / DC_, j = e - m * DC_;
                    // pass-A record: msg-plane offset folded -> (j*ZM+m*Z)<<9 | s
                    ws[LST_OFF + p++] = ((j * ZM + m * Z_) << 9) | shl[e];
                }
            }
        }
        return;
    }
    // ---- pre-transpose: block = swizzled (b, 64-z tile) ----
    __shared__ float tile[N_ * 65];           // [n][zl], pad 65 to break conflicts
    const int x = blockIdx.x & 7;
    const int k = blockIdx.x >> 3;            // 0..23
    const int b = x + 8 * (k & 3);            // b % 8 == x  -> XCD locality
    const int t = k >> 2;                     // 0..5
    const int z0 = t * 64;
    const float* src = xa + (size_t)b * ZN + (size_t)z0 * N_;
    for (int i = tid; i < 64 * N_; i += 384) {  // contiguous 17 KB read
        int r = i / N_, n = i - r * N_;
        tile[n * 65 + r] = src[i];
    }
    __syncthreads();
    float* dst = xat_dst + (size_t)b * ZN + z0;
    for (int i = tid; i < 64 * N_; i += 384) {
        int n = i >> 6, zl = i & 63;
        dst[n * Z_ + zl] = tile[n * 65 + zl];
    }
}

// ==================== pass B: check-node update ====================
// block = swizzled (b, m), thread = z. Old c2v read from own plane bytes
// (stride-1 across lanes -> 1 line/wave); writes 7 plane bytes likewise.
__global__ __launch_bounds__(384)
void k_passB(const float* __restrict__ cw, const int* __restrict__ ws_tbl,
             signed char* __restrict__ msg, const float* __restrict__ src_g,
             int it, int use_init)
{
    __shared__ int cevs[DC_];
    const int x = blockIdx.x & 7;
    const int k = blockIdx.x >> 3;            // 0..183
    const int b = x + 8 * (k & 3);            // b % 8 == x
    const int m = k >> 2;                     // 0..45
    const int z = threadIdx.x;
    if (z < DC_) cevs[z] = ws_tbl[EVS_OFF + m * DC_ + z];
    __syncthreads();

    const float* src = src_g + (size_t)b * ZN;       // xat at it=0, lt otherwise
    signed char* mp = msg + (size_t)b * MSB + m * Z_ + z;   // plane j at +j*ZM
    const float w = cw[it];

    float m1 = 1e30f, m2 = 1e30f;
    int f = 0, negb = 0;
    #pragma unroll
    for (int j = 0; j < DC_; ++j) {
        int rec = cevs[j];
        int s = rec & 511;
        int zr = z + s; if (zr >= Z_) zr -= Z_;
        int c2 = use_init ? 0 : (int)mp[j * ZM];      // own old message, exact int
        // identical operand order to JAX: fl(fl(llr + tot) - c2v), then clip
        float v = src[(rec >> 9) + zr] - 0.5f * (float)c2;
        v = fminf(fmaxf(v, -20.0f), 20.0f);
        negb |= (v < 0.0f) << j;
        float a = fabsf(v);
        if (a < m1) { m2 = m1; m1 = a; f = j; }
        else if (a < m2) { m2 = a; }
    }
    // quantize-STE forward: clip(rint(2*w*min)/2, +-7.5), kept as int half-steps
    float r1 = fminf(fmaxf(rintf(w * m1 * 2.0f), -15.0f), 15.0f);
    float r2 = fminf(fmaxf(rintf(w * m2 * 2.0f), -15.0f), 15.0f);
    const int q1 = (int)r1, q2 = (int)r2;
    const int par = __popc(negb);
    #pragma unroll
    for (int j = 0; j < DC_; ++j) {
        int q  = (j == f) ? q2 : q1;
        int sj = (par - ((negb >> j) & 1)) & 1;   // parity of other edges' signs
        mp[j * ZM] = (signed char)(sj ? -q : q);
    }
}

// ==================== pass A: variable totals ====================
// block = swizzled (b, n), thread = z. Per edge: one plane byte-gather
// (64 consecutive bytes per wave -> 1-2 lines) + int add.
__global__ __launch_bounds__(384)
void k_passA(const float* __restrict__ xat, const int* __restrict__ ws_tbl,
             const signed char* __restrict__ msg, float* __restrict__ dst)
{
    __shared__ int vlist[16];                 // dv <= 16 in practice (avg 4.7)
    __shared__ int s_cnt;
    const int x = blockIdx.x & 7;
    const int k = blockIdx.x >> 3;            // 0..271
    const int b = x + 8 * (k & 3);            // b % 8 == x
    const int n = k >> 2;                     // 0..67
    const int tid = threadIdx.x;
    const int o = ws_tbl[OFFS_OFF + n];
    const int e = ws_tbl[OFFS_OFF + n + 1];
    if (tid == 0) s_cnt = e - o;
    if (tid < e - o && tid < 16) vlist[tid] = ws_tbl[LST_OFF + o + tid];
    __syncthreads();

    const int z = tid;
    const signed char* mb = msg + (size_t)b * MSB;
    const int cnt = s_cnt;                    // wave-uniform (Z = 6 full waves)
    int t2 = 0;
    for (int q = 0; q < cnt; ++q) {
        int rec = (q < 16) ? vlist[q] : ws_tbl[LST_OFF + o + q];
        int s = rec & 511;
        int zs = z - s; if (zs < 0) zs += Z_;
        t2 += (int)mb[(rec >> 9) + zs];       // exact int half-steps
    }
    // fl(llr + tot); dst layout == out layout [b][n*Z+z]
    dst[(size_t)b * ZN + n * Z_ + z] =
        xat[(size_t)b * ZN + n * Z_ + z] + 0.5f * (float)t2;
}

// ==================== fallback: single-block-per-batch kernel (small ws) ====================
#define INIT_STATE ((16u << 10) | (16u << 15))
__device__ __forceinline__ int decode2(unsigned st, int j) {
    int neg   = (st >> j) & 1;
    int q1    = (int)((st >> 10) & 31) - 16;
    int q2    = (int)((st >> 15) & 31) - 16;
    int first = (int)((st >> 7) & 7);
    int q     = (j == first) ? q2 : q1;
    int par   = (__popc(st & 127u) - neg) & 1;
    return par ? -q : q;
}

__global__ __launch_bounds__(1024)
void ldpc_decode_kernel(const float* __restrict__ xa,
                        const float* __restrict__ cw,
                        const int*   __restrict__ vn_idx,
                        const int*   __restrict__ shifts,
                        float* out, int iters)
{
    __shared__ short tot[ZN];
    __shared__ int   evs[E_];
    __shared__ int   offs[N_ + 1];
    __shared__ int   lists[E_];
    __shared__ float wlds[8];

    const int tid = threadIdx.x;
    const int b   = blockIdx.x;
    const float* xab = xa + (size_t)b * ZN;
    float* outb = out + (size_t)b * ZN;
    int* stateg = (int*)outb;

    if (tid < E_) evs[tid] = vn_idx[tid] | (shifts[tid] << 7);
    if (tid < iters && tid < 8) wlds[tid] = cw[tid];
    __syncthreads();
    if (tid < N_) {
        int c = 0;
        for (int e = 0; e < E_; ++e) c += ((evs[e] & 127) == tid);
        offs[tid + 1] = c;
    }
    if (tid == 0) offs[0] = 0;
    __syncthreads();
    if (tid == 0) { for (int n = 0; n < N_; ++n) offs[n + 1] += offs[n]; }
    __syncthreads();
    if (tid < N_) {
        int p = offs[tid];
        for (int e = 0; e < E_; ++e) {
            int rec = evs[e];
            if ((rec & 127) == tid) {
                int s = rec >> 7;
                lists[p++] = s | ((e / DC_) << 9) | ((e % DC_) << 15);
            }
        }
    }
    __syncthreads();

    for (int i = tid; i < ZM; i += 1024) stateg[i] = (int)INIT_STATE;
    __syncthreads();

    for (int it = 0; it < iters; ++it) {
        for (int i = tid; i < ZN; i += 1024) {
            int z = i / N_, n = i - z * N_, t2 = 0;
            int kend = offs[n + 1];
            for (int k = offs[n]; k < kend; ++k) {
                int rec = lists[k];
                int s = rec & 511, m = (rec >> 9) & 63, j = rec >> 15;
                int zs = z - s; if (zs < 0) zs += Z_;
                t2 += decode2((unsigned)stateg[zs * M_ + m], j);
            }
            tot[i] = (short)t2;
        }
        __syncthreads();
        const float w = wlds[it];
        for (int i = tid; i < ZM; i += 1024) {
            int z = i / M_, m = i - z * M_;
            unsigned st = (unsigned)stateg[i];
            float m1 = 1e30f, m2 = 1e30f;
            int f = 0, negb = 0;
            #pragma unroll
            for (int j = 0; j < DC_; ++j) {
                int rec = evs[m * DC_ + j];
                int vn = rec & 127, s = rec >> 7;
                int zr = z + s; if (zr >= Z_) zr -= Z_;
                int c2 = decode2(st, j);
                int idx = zr * N_ + vn;
                float v = (xab[idx] + 0.5f * (float)tot[idx]) - 0.5f * (float)c2;
                v = fminf(fmaxf(v, -20.0f), 20.0f);
                negb |= (v < 0.0f) << j;
                float a = fabsf(v);
                if (a < m1) { m2 = m1; m1 = a; f = j; }
                else if (a < m2) { m2 = a; }
            }
            float r1 = fminf(fmaxf(rintf(w * m1 * 2.0f), -15.0f), 15.0f);
            float r2 = fminf(fmaxf(rintf(w * m2 * 2.0f), -15.0f), 15.0f);
            stateg[i] = (int)(unsigned)(negb | (f << 7) | (((int)r1 + 16) << 10) | (((int)r2 + 16) << 15));
        }
        __syncthreads();
    }

    for (int i = tid; i < ZN; i += 1024) {
        int z = i / N_, n = i - z * N_, t2 = 0;
        int kend = offs[n + 1];
        for (int k = offs[n]; k < kend; ++k) {
            int rec = lists[k];
            int s = rec & 511, m = (rec >> 9) & 63, j = rec >> 15;
            int zs = z - s; if (zs < 0) zs += Z_;
            t2 += decode2((unsigned)stateg[zs * M_ + m], j);
        }
        tot[i] = (short)t2;
    }
    __syncthreads();
    for (int i = tid; i < ZN; i += 1024) {
        int n = i / Z_, z = i - n * Z_;
        outb[i] = xab[z * N_ + n] + 0.5f * (float)tot[z * N_ + n];
    }
}

extern "C" void kernel_launch(void* const* d_in, const int* in_sizes, int n_in,
                              void* d_out, int out_size, void* d_ws, size_t ws_size,
                              hipStream_t stream) {
    const float* xa = (const float*)d_in[0];
    const float* cw = (const float*)d_in[1];
    const int* vn   = (const int*)d_in[2];
    // d_in[3] = cn_idx: repeat(arange(M), dc) by construction — implicit.
    const int* sh   = (const int*)d_in[4];
    int iters = in_sizes[1];
    float* outp = (float*)d_out;

    if (ws_size >= (size_t)WS_INTS * sizeof(int)) {
        int*         ws  = (int*)d_ws;
        float*       xat = (float*)d_ws + XAT_OFF;
        float*       lt  = (float*)d_ws + LT_OFF;
        signed char* msg = (signed char*)(ws + MSG_OFF);

        if (iters == 0) {   // out = transpose(xa); tables block is harmless
            hipLaunchKernelGGL(k_pre_tables, dim3(B_ * 6 + 1), dim3(384), 0, stream,
                               xa, vn, sh, ws, outp);
            return;
        }
        hipLaunchKernelGGL(k_pre_tables, dim3(B_ * 6 + 1), dim3(384), 0, stream,
                           xa, vn, sh, ws, xat);
        // it = 0: lt_old == xat, all old c2v == 0
        hipLaunchKernelGGL(k_passB, dim3(B_ * M_), dim3(384), 0, stream,
                           cw, ws, msg, xat, 0, 1);
        for (int it = 1; it < iters; ++it) {
            hipLaunchKernelGGL(k_passA, dim3(B_ * N_), dim3(384), 0, stream,
                               xat, ws, msg, lt);
            hipLaunchKernelGGL(k_passB, dim3(B_ * M_), dim3(384), 0, stream,
                               cw, ws, msg, lt, it, 0);
        }
        hipLaunchKernelGGL(k_passA, dim3(B_ * N_), dim3(384), 0, stream,
                           xat, ws, msg, outp);
    } else {
        hipLaunchKernelGGL(ldpc_decode_kernel, dim3(B_), dim3(1024), 0, stream,
                           xa, cw, vn, sh, outp, iters);
    }
}